// Round 12
// baseline (104.297 us; speedup 1.0000x reference)
//
#include <hip/hip_runtime.h>
#include <hip/hip_bf16.h>
#include <hip/hip_fp16.h>

// B=4, C=384, H=W=56 (S=3136, padded 3200), NH=12, HD=32, WS=7, pad=3.
#define S_HW 3136
#define SP   3200
#define IMG_W 56
#define C_DIM 384
#define NH_DIM 12
#define QKV_C 1152

// attention tiling
#define TB 16              // tile is TB x TB pixels
#define HALO 22            // TB + 6
#define NPX 484            // HALO*HALO
#define PLANE_B 3880       // NPX*8 rounded up (+8) to stagger plane banks

typedef float f32x4 __attribute__((ext_vector_type(4)));
typedef short bf16x8 __attribute__((ext_vector_type(8)));
typedef _Float16 f16x2 __attribute__((ext_vector_type(2)));

__device__ __forceinline__ void gld_lds16(const void* g, void* lds) {
    __builtin_amdgcn_global_load_lds(
        (const __attribute__((address_space(1))) void*)g,
        (__attribute__((address_space(3))) void*)lds, 16, 0, 0);
}

__device__ __forceinline__ float u2f(unsigned int u) { return __uint_as_float(u); }
__device__ __forceinline__ unsigned int f2bf_bits(float f) {
    unsigned int u = __float_as_uint(f);
    u += 0x7FFF + ((u >> 16) & 1);   // round-nearest-even
    return u >> 16;
}
__device__ __forceinline__ unsigned int f2h_bits(float f) {
    return (unsigned int)__half_as_ushort(__float2half(f));
}

// pair-swap (lanes 2i <-> 2i+1) via quad_perm [1,0,3,2] = 0xB1; validated
// update_dpp semantics from r7 (bit-exact). Pairs share the exec predicate.
__device__ __forceinline__ float pair_sum(float v) {
    int o = __builtin_amdgcn_update_dpp(0, __float_as_int(v), 0xB1, 0xF, 0xF, true);
    return v + __uint_as_float((unsigned int)o);
}

// ---------------------------------------------------------------------------
__global__ __launch_bounds__(256) void convert_w2_kernel(
    const float* __restrict__ a, int na, __hip_bfloat16* __restrict__ oa,
    const float* __restrict__ b, int nb, __hip_bfloat16* __restrict__ ob)
{
    int i = blockIdx.x * 256 + threadIdx.x;
    if (i < na) oa[i] = __float2bfloat16(a[i]);
    else if (i < na + nb) ob[i - na] = __float2bfloat16(b[i - na]);
}

// ---------------------------------------------------------------------------
// x [4][384][3136] f32  ->  x_t [4][3200][384] bf16 (transpose + convert)
// ---------------------------------------------------------------------------
__global__ __launch_bounds__(256) void transpose_convert_kernel(
    const float* __restrict__ x, __hip_bfloat16* __restrict__ xt)
{
    __shared__ float t[32][33];
    const int b = blockIdx.z;
    const int c0 = blockIdx.y * 32, s0 = blockIdx.x * 32;
    const int tid = threadIdx.x;

    const int lc = tid >> 3, ls = (tid & 7) * 4;
    float4 v = *reinterpret_cast<const float4*>(
        &x[((size_t)b * C_DIM + c0 + lc) * S_HW + s0 + ls]);
    t[lc][ls + 0] = v.x; t[lc][ls + 1] = v.y;
    t[lc][ls + 2] = v.z; t[lc][ls + 3] = v.w;
    __syncthreads();

    const int ws = tid >> 3, wc = (tid & 7) * 4;
    uint2 pk;
    pk.x = f2bf_bits(t[wc + 0][ws]) | (f2bf_bits(t[wc + 1][ws]) << 16);
    pk.y = f2bf_bits(t[wc + 2][ws]) | (f2bf_bits(t[wc + 3][ws]) << 16);
    *reinterpret_cast<uint2*>(
        &xt[((size_t)b * SP + s0 + ws) * C_DIM + c0 + wc]) = pk;
}

// ---------------------------------------------------------------------------
// bf16 MFMA GEMM (m97 structure), tile 128 x (NF*32), BK=32, 4 waves (2x2).
// ---------------------------------------------------------------------------
template <bool TRANS_OUT, int NF, typename OutT>
__global__ __launch_bounds__(256) void gemm_bf16_mfma(
    const __hip_bfloat16* __restrict__ A,    // [O][K]
    const __hip_bfloat16* __restrict__ Bt,   // [batch][SP][K]
    const float* __restrict__ bias,
    OutT* __restrict__ Y,
    int O, int K, float qscale, int qrows)
{
    constexpr int BN = NF * 32;
    __shared__ char smem[8192 + BN * 64];
    char* As = smem;             // [128][32] bf16 linear
    char* Bs = smem + 8192;      // [BN][32] bf16 linear

    const int b   = blockIdx.z;
    const int m0  = blockIdx.y * 128;
    const int n0  = blockIdx.x * BN;
    const int tid = threadIdx.x;
    const int w = tid >> 6, l = tid & 63;
    const int wr = w >> 1, wc = w & 1;

    const int srow = l >> 2;
    const int skk  = (l & 3) * 8;

    const __hip_bfloat16* Bb = Bt + (size_t)b * SP * K;

    f32x4 acc[4][NF];
    #pragma unroll
    for (int i = 0; i < 4; ++i)
        #pragma unroll
        for (int j = 0; j < NF; ++j) {
            f32x4 z = {0.f, 0.f, 0.f, 0.f};
            acc[i][j] = z;
        }

    const int frow = l & 15;
    const int fk   = (l >> 4) * 16;

    for (int k0 = 0; k0 < K; k0 += 32) {
        #pragma unroll
        for (int j = 0; j < 2; ++j) {
            const int chunk = w * 2 + j;
            const int m = chunk * 16 + srow;
            gld_lds16(A + (size_t)(m0 + m) * K + k0 + skk, As + chunk * 1024);
        }
        if (NF == 4) {
            #pragma unroll
            for (int j = 0; j < 2; ++j) {
                const int chunk = w * 2 + j;
                const int m = chunk * 16 + srow;
                gld_lds16(Bb + (size_t)(n0 + m) * K + k0 + skk, Bs + chunk * 1024);
            }
        } else {
            const int m = w * 16 + srow;
            gld_lds16(Bb + (size_t)(n0 + m) * K + k0 + skk, Bs + w * 1024);
        }
        __syncthreads();
        bf16x8 af[4], bfr[NF];
        #pragma unroll
        for (int mi = 0; mi < 4; ++mi)
            af[mi] = *reinterpret_cast<const bf16x8*>(
                As + (wr * 64 + mi * 16 + frow) * 64 + fk);
        #pragma unroll
        for (int ni = 0; ni < NF; ++ni)
            bfr[ni] = *reinterpret_cast<const bf16x8*>(
                Bs + (wc * (NF * 16) + ni * 16 + frow) * 64 + fk);
        #pragma unroll
        for (int mi = 0; mi < 4; ++mi)
            #pragma unroll
            for (int ni = 0; ni < NF; ++ni)
                acc[mi][ni] = __builtin_amdgcn_mfma_f32_16x16x32_bf16(
                    af[mi], bfr[ni], acc[mi][ni], 0, 0, 0);
        __syncthreads();
    }

    const int crow0 = (l >> 4) * 4;
    const int ccol  = l & 15;
    if (TRANS_OUT) {
        __hip_bfloat16* Yb = (__hip_bfloat16*)Y + (size_t)b * SP * O;
        #pragma unroll
        for (int ni = 0; ni < NF; ++ni) {
            const int col = n0 + wc * (NF * 16) + ni * 16 + ccol;
            if (col >= S_HW) continue;
            #pragma unroll
            for (int mi = 0; mi < 4; ++mi) {
                const int row0 = m0 + wr * 64 + mi * 16 + crow0;
                const float sc = (row0 < qrows) ? qscale : 1.f;
                float v0 = (acc[mi][ni][0] + bias[row0 + 0]) * sc;
                float v1 = (acc[mi][ni][1] + bias[row0 + 1]) * sc;
                float v2 = (acc[mi][ni][2] + bias[row0 + 2]) * sc;
                float v3 = (acc[mi][ni][3] + bias[row0 + 3]) * sc;
                uint2 pk;
                pk.x = f2h_bits(v0) | (f2h_bits(v1) << 16);
                pk.y = f2h_bits(v2) | (f2h_bits(v3) << 16);
                *reinterpret_cast<uint2*>(&Yb[(size_t)col * O + row0]) = pk;
            }
        }
    } else {
        float* Yb = (float*)Y + (size_t)b * O * S_HW;
        #pragma unroll
        for (int ni = 0; ni < NF; ++ni) {
            const int col = n0 + wc * (NF * 16) + ni * 16 + ccol;
            if (col >= S_HW) continue;
            #pragma unroll
            for (int mi = 0; mi < 4; ++mi) {
                #pragma unroll
                for (int r = 0; r < 4; ++r) {
                    const int row = m0 + wr * 64 + mi * 16 + crow0 + r;
                    float v = acc[mi][ni][r] + bias[row];
                    if (row < qrows) v *= qscale;
                    Yb[(size_t)row * S_HW + col] = v;
                }
            }
        }
    }
}

// ---------------------------------------------------------------------------
// Neighborhood attention, LDS-staged halo, 2 THREADS PER PIXEL (channel halves
// 0-15 / 16-31 on adjacent lanes). Same LDS layout as r6/r11. QK partial dots
// combined with one quad_perm pair-swap add per logit; softmax redundant in
// both lanes; PV each lane accumulates its own 16 channels.
// 512-thr blocks: doubles resident waves/CU (grid was the occupancy limit).
// ---------------------------------------------------------------------------
__global__ __launch_bounds__(512) void na_attn_kernel(
    const __hip_bfloat16* __restrict__ qkvt, const float* __restrict__ rel_bias,
    __hip_bfloat16* __restrict__ outt)
{
    __shared__ alignas(16) char halo[8 * PLANE_B];   // ~31 KB

    const int blk  = blockIdx.x;          // b*NH*16 + nh*16 + tile
    const int tile = blk & 15;
    const int bn   = blk >> 4;
    const int nh   = bn % NH_DIM;
    const int b    = bn / NH_DIM;
    const int th0  = (tile >> 2) * TB;
    const int tw0  = (tile & 3) * TB;

    const int tid  = threadIdx.x;
    const int px   = tid >> 1;            // 0..255 pixel within tile
    const int half = tid & 1;             // channel half
    const int ty = px >> 4, tx = px & 15;
    const int h = th0 + ty, w = tw0 + tx;
    const bool valid = (h < 56) && (w < 56);
    const int s = h * IMG_W + w;

    const __hip_bfloat16* base = qkvt + (size_t)b * SP * QKV_C;
    const int co = nh * 32;
    const int pl0 = 4 * half;             // this lane's first LDS plane

    // ---- stage K halo (512 threads, 4 iters over 484*4 chunks)
    #pragma unroll
    for (int i = 0; i < 4; ++i) {
        const int idx = tid + i * 512;
        if (idx < NPX * 4) {
            const int p = idx >> 2, g = idx & 3;
            const int hy = p / HALO, hx = p - hy * HALO;
            const int y = min(max(th0 - 3 + hy, 0), 55);
            const int x = min(max(tw0 - 3 + hx, 0), 55);
            const uint4 v = *reinterpret_cast<const uint4*>(
                base + (size_t)(y * IMG_W + x) * QKV_C + C_DIM + co + g * 8);
            uint2 lo; lo.x = v.x; lo.y = v.y;
            uint2 hi; hi.x = v.z; hi.y = v.w;
            *reinterpret_cast<uint2*>(&halo[(2 * g + 0) * PLANE_B + p * 8]) = lo;
            *reinterpret_cast<uint2*>(&halo[(2 * g + 1) * PLANE_B + p * 8]) = hi;
        }
    }

    // ---- own q: 16 channels for this half (8 packed f16 pairs)
    unsigned int qreg[8];
    if (valid) {
        const uint4* qp = reinterpret_cast<const uint4*>(
            base + (size_t)s * QKV_C + co + 16 * half);
        uint4 q0 = qp[0], q1 = qp[1];
        qreg[0] = q0.x; qreg[1] = q0.y; qreg[2] = q0.z; qreg[3] = q0.w;
        qreg[4] = q1.x; qreg[5] = q1.y; qreg[6] = q1.z; qreg[7] = q1.w;
    }
    __syncthreads();

    // ---- QK: 49 partial dots (16 ch) from LDS, pair-combined
    float logits[49];
    if (valid) {
        #pragma unroll
        for (int di = 0; di < 7; ++di) {
            #pragma unroll
            for (int dj = 0; dj < 7; ++dj) {
                const int hp = (ty + di) * HALO + (tx + dj);
                const char* hb = halo + hp * 8;
                float acc0 = 0.f, acc1 = 0.f;
                #pragma unroll
                for (int pl = 0; pl < 4; ++pl) {
                    uint2 kk = *reinterpret_cast<const uint2*>(
                        hb + (pl0 + pl) * PLANE_B);
#if __has_builtin(__builtin_amdgcn_fdot2)
                    acc0 = __builtin_amdgcn_fdot2(
                        __builtin_bit_cast(f16x2, qreg[2 * pl]),
                        __builtin_bit_cast(f16x2, kk.x), acc0, false);
                    acc1 = __builtin_amdgcn_fdot2(
                        __builtin_bit_cast(f16x2, qreg[2 * pl + 1]),
                        __builtin_bit_cast(f16x2, kk.y), acc1, false);
#else
                    f16x2 qa = __builtin_bit_cast(f16x2, qreg[2 * pl]);
                    f16x2 qb = __builtin_bit_cast(f16x2, qreg[2 * pl + 1]);
                    f16x2 ka = __builtin_bit_cast(f16x2, kk.x);
                    f16x2 kb = __builtin_bit_cast(f16x2, kk.y);
                    acc0 += (float)qa[0] * (float)ka[0] + (float)qa[1] * (float)ka[1];
                    acc1 += (float)qb[0] * (float)kb[0] + (float)qb[1] * (float)kb[1];
#endif
                }
                logits[di * 7 + dj] =
                    pair_sum(acc0 + acc1) + rel_bias[(nh * 7 + di) * 7 + dj];
            }
        }
    }
    __syncthreads();    // all K reads done before V overwrites

    // ---- stage V halo into the same buffer
    #pragma unroll
    for (int i = 0; i < 4; ++i) {
        const int idx = tid + i * 512;
        if (idx < NPX * 4) {
            const int p = idx >> 2, g = idx & 3;
            const int hy = p / HALO, hx = p - hy * HALO;
            const int y = min(max(th0 - 3 + hy, 0), 55);
            const int x = min(max(tw0 - 3 + hx, 0), 55);
            const uint4 v = *reinterpret_cast<const uint4*>(
                base + (size_t)(y * IMG_W + x) * QKV_C + 2 * C_DIM + co + g * 8);
            uint2 lo; lo.x = v.x; lo.y = v.y;
            uint2 hi; hi.x = v.z; hi.y = v.w;
            *reinterpret_cast<uint2*>(&halo[(2 * g + 0) * PLANE_B + p * 8]) = lo;
            *reinterpret_cast<uint2*>(&halo[(2 * g + 1) * PLANE_B + p * 8]) = hi;
        }
    }

    // ---- softmax (redundant per pair, deterministic); pack p to bf16 pairs
    unsigned int ppk[25];
    float inv = 0.f;
    if (valid) {
        float mx = logits[0];
        #pragma unroll
        for (int i = 1; i < 49; ++i) mx = fmaxf(mx, logits[i]);
        float sum = 0.f;
        #pragma unroll
        for (int i = 0; i < 24; ++i) {
            float e0 = __expf(logits[2 * i] - mx);
            float e1 = __expf(logits[2 * i + 1] - mx);
            sum += e0 + e1;
            ppk[i] = f2bf_bits(e0) << 16 | f2bf_bits(e1);
        }
        {
            float e0 = __expf(logits[48] - mx);
            sum += e0;
            ppk[24] = f2bf_bits(e0) << 16;
        }
        inv = 1.f / sum;
    }
    __syncthreads();

    // ---- PV: accumulate this half's 16 channels via fma_mix
    if (valid) {
        float o[16];
        #pragma unroll
        for (int c = 0; c < 16; ++c) o[c] = 0.f;

        #pragma unroll
        for (int n = 0; n < 49; ++n) {
            const unsigned int pu = ppk[n >> 1];
            const float pv = (n & 1) ? u2f(pu << 16) : u2f(pu & 0xFFFF0000u);
            const int di = n / 7, dj = n % 7;
            const int hp = (ty + di) * HALO + (tx + dj);
            const char* hb = halo + hp * 8;
            #pragma unroll
            for (int pl = 0; pl < 4; ++pl) {
                uint2 vv = *reinterpret_cast<const uint2*>(
                    hb + (pl0 + pl) * PLANE_B);
                f16x2 va = __builtin_bit_cast(f16x2, vv.x);
                f16x2 vb = __builtin_bit_cast(f16x2, vv.y);
                o[4 * pl + 0] = fmaf((float)va[0], pv, o[4 * pl + 0]);
                o[4 * pl + 1] = fmaf((float)va[1], pv, o[4 * pl + 1]);
                o[4 * pl + 2] = fmaf((float)vb[0], pv, o[4 * pl + 2]);
                o[4 * pl + 3] = fmaf((float)vb[1], pv, o[4 * pl + 3]);
            }
        }

        uint4* dst = reinterpret_cast<uint4*>(
            outt + ((size_t)b * SP + s) * C_DIM + co + 16 * half);
        #pragma unroll
        for (int g = 0; g < 2; ++g) {
            uint4 pk;
            pk.x = f2bf_bits(o[8 * g + 0] * inv) | (f2bf_bits(o[8 * g + 1] * inv) << 16);
            pk.y = f2bf_bits(o[8 * g + 2] * inv) | (f2bf_bits(o[8 * g + 3] * inv) << 16);
            pk.z = f2bf_bits(o[8 * g + 4] * inv) | (f2bf_bits(o[8 * g + 5] * inv) << 16);
            pk.w = f2bf_bits(o[8 * g + 6] * inv) | (f2bf_bits(o[8 * g + 7] * inv) << 16);
            dst[g] = pk;
        }
    }
}

// ---------------------------------------------------------------------------
extern "C" void kernel_launch(void* const* d_in, const int* in_sizes, int n_in,
                              void* d_out, int out_size, void* d_ws, size_t ws_size,
                              hipStream_t stream) {
    const float* x        = (const float*)d_in[0];
    const float* w_qkv    = (const float*)d_in[1];
    const float* b_qkv    = (const float*)d_in[2];
    const float* w_proj   = (const float*)d_in[3];
    const float* b_proj   = (const float*)d_in[4];
    const float* rel_bias = (const float*)d_in[5];
    float* out = (float*)d_out;

    __hip_bfloat16* xt   = (__hip_bfloat16*)d_ws;
    __hip_bfloat16* wq   = xt + (size_t)4 * SP * C_DIM;
    __hip_bfloat16* wp   = wq + (size_t)QKV_C * C_DIM;
    __hip_bfloat16* qkvt = wp + (size_t)C_DIM * C_DIM;
    __hip_bfloat16* att  = qkvt + (size_t)4 * SP * QKV_C;

    const float scale = 0.17677669529663687f;  // 32^-0.5
    const int nwq = QKV_C * C_DIM, nwp = C_DIM * C_DIM;

    convert_w2_kernel<<<dim3((nwq + nwp + 255) / 256), 256, 0, stream>>>(
        w_qkv, nwq, wq, w_proj, nwp, wp);
    transpose_convert_kernel<<<dim3(98, 12, 4), dim3(256), 0, stream>>>(x, xt);

    // qkv projection: O=1152, K=384 -> [b][SP][1152] f16 (q pre-scaled)
    gemm_bf16_mfma<true, 4, __hip_bfloat16><<<dim3(25, 9, 4), 256, 0, stream>>>(
        wq, xt, b_qkv, qkvt, QKV_C, C_DIM, scale, C_DIM);

    // attention: 4 b * 12 heads * 16 tiles; 512 thr = 2 per pixel
    na_attn_kernel<<<dim3(4 * NH_DIM * 16), 512, 0, stream>>>(qkvt, rel_bias, att);

    // output projection: O=384, K=384, tile 128x64 -> 600 blocks, fp32 out
    gemm_bf16_mfma<false, 2, float><<<dim3(50, 3, 4), 256, 0, stream>>>(
        wp, att, b_proj, out, C_DIM, C_DIM, 1.f, 0);
}

// Round 13
// 101.375 us; speedup vs baseline: 1.0288x; 1.0288x over previous
//
#include <hip/hip_runtime.h>
#include <hip/hip_bf16.h>
#include <hip/hip_fp16.h>

// B=4, C=384, H=W=56 (S=3136, padded 3200), NH=12, HD=32, WS=7, pad=3.
#define S_HW 3136
#define SP   3200
#define IMG_W 56
#define C_DIM 384
#define NH_DIM 12
#define QKV_C 1152

// attention tiling
#define TB 16              // tile is TB x TB pixels
#define HALO 22            // TB + 6
#define NPX 484            // HALO*HALO
// Plane stride: 994 dwords; 994 % 32 == 2 -> adjacent planes offset +2 banks,
// so the two half-lanes of a pixel interleave onto disjoint bank phases.
#define PLANE_B 3976

typedef float f32x4 __attribute__((ext_vector_type(4)));
typedef short bf16x8 __attribute__((ext_vector_type(8)));
typedef _Float16 f16x2 __attribute__((ext_vector_type(2)));

__device__ __forceinline__ void gld_lds16(const void* g, void* lds) {
    __builtin_amdgcn_global_load_lds(
        (const __attribute__((address_space(1))) void*)g,
        (__attribute__((address_space(3))) void*)lds, 16, 0, 0);
}

__device__ __forceinline__ float u2f(unsigned int u) { return __uint_as_float(u); }
__device__ __forceinline__ unsigned int f2bf_bits(float f) {
    unsigned int u = __float_as_uint(f);
    u += 0x7FFF + ((u >> 16) & 1);   // round-nearest-even
    return u >> 16;
}
__device__ __forceinline__ unsigned int f2h_bits(float f) {
    return (unsigned int)__half_as_ushort(__float2half(f));
}

// pair-swap (lanes 2i <-> 2i+1) via quad_perm [1,0,3,2] = 0xB1
// (validated bit-exact in r12: absmax matched r11 exactly)
__device__ __forceinline__ float pair_sum(float v) {
    int o = __builtin_amdgcn_update_dpp(0, __float_as_int(v), 0xB1, 0xF, 0xF, true);
    return v + __uint_as_float((unsigned int)o);
}

// ---------------------------------------------------------------------------
__global__ __launch_bounds__(256) void convert_w2_kernel(
    const float* __restrict__ a, int na, __hip_bfloat16* __restrict__ oa,
    const float* __restrict__ b, int nb, __hip_bfloat16* __restrict__ ob)
{
    int i = blockIdx.x * 256 + threadIdx.x;
    if (i < na) oa[i] = __float2bfloat16(a[i]);
    else if (i < na + nb) ob[i - na] = __float2bfloat16(b[i - na]);
}

// ---------------------------------------------------------------------------
// x [4][384][3136] f32  ->  x_t [4][3200][384] bf16 (transpose + convert)
// ---------------------------------------------------------------------------
__global__ __launch_bounds__(256) void transpose_convert_kernel(
    const float* __restrict__ x, __hip_bfloat16* __restrict__ xt)
{
    __shared__ float t[32][33];
    const int b = blockIdx.z;
    const int c0 = blockIdx.y * 32, s0 = blockIdx.x * 32;
    const int tid = threadIdx.x;

    const int lc = tid >> 3, ls = (tid & 7) * 4;
    float4 v = *reinterpret_cast<const float4*>(
        &x[((size_t)b * C_DIM + c0 + lc) * S_HW + s0 + ls]);
    t[lc][ls + 0] = v.x; t[lc][ls + 1] = v.y;
    t[lc][ls + 2] = v.z; t[lc][ls + 3] = v.w;
    __syncthreads();

    const int ws = tid >> 3, wc = (tid & 7) * 4;
    uint2 pk;
    pk.x = f2bf_bits(t[wc + 0][ws]) | (f2bf_bits(t[wc + 1][ws]) << 16);
    pk.y = f2bf_bits(t[wc + 2][ws]) | (f2bf_bits(t[wc + 3][ws]) << 16);
    *reinterpret_cast<uint2*>(
        &xt[((size_t)b * SP + s0 + ws) * C_DIM + c0 + wc]) = pk;
}

// ---------------------------------------------------------------------------
// bf16 MFMA GEMM (m97 structure), tile 128 x (NF*32), 4 waves (2x2).
// 2 k-subtiles (BK=32 each) per barrier pair: halves barrier count for
// small K (=384 -> 6 outer iterations). Accumulation order identical to the
// single-subtile version (bit-exact).
// ---------------------------------------------------------------------------
template <bool TRANS_OUT, int NF, typename OutT>
__global__ __launch_bounds__(256) void gemm_bf16_mfma(
    const __hip_bfloat16* __restrict__ A,    // [O][K]
    const __hip_bfloat16* __restrict__ Bt,   // [batch][SP][K]
    const float* __restrict__ bias,
    OutT* __restrict__ Y,
    int O, int K, float qscale, int qrows)
{
    constexpr int BN = NF * 32;
    __shared__ char smem[16384 + BN * 128];
    char* As0 = smem;                  // [128][32] bf16 linear, k0
    char* As1 = smem + 8192;           // k0+32
    char* Bs0 = smem + 16384;          // [BN][32], k0
    char* Bs1 = smem + 16384 + BN * 64;// k0+32

    const int b   = blockIdx.z;
    const int m0  = blockIdx.y * 128;
    const int n0  = blockIdx.x * BN;
    const int tid = threadIdx.x;
    const int w = tid >> 6, l = tid & 63;
    const int wr = w >> 1, wc = w & 1;

    const int srow = l >> 2;
    const int skk  = (l & 3) * 8;

    const __hip_bfloat16* Bb = Bt + (size_t)b * SP * K;

    f32x4 acc[4][NF];
    #pragma unroll
    for (int i = 0; i < 4; ++i)
        #pragma unroll
        for (int j = 0; j < NF; ++j) {
            f32x4 z = {0.f, 0.f, 0.f, 0.f};
            acc[i][j] = z;
        }

    const int frow = l & 15;
    const int fk   = (l >> 4) * 16;

    for (int k0 = 0; k0 < K; k0 += 64) {
        #pragma unroll
        for (int j = 0; j < 2; ++j) {
            const int chunk = w * 2 + j;
            const int m = chunk * 16 + srow;
            gld_lds16(A + (size_t)(m0 + m) * K + k0 + skk,      As0 + chunk * 1024);
            gld_lds16(A + (size_t)(m0 + m) * K + k0 + 32 + skk, As1 + chunk * 1024);
        }
        if (NF == 4) {
            #pragma unroll
            for (int j = 0; j < 2; ++j) {
                const int chunk = w * 2 + j;
                const int m = chunk * 16 + srow;
                gld_lds16(Bb + (size_t)(n0 + m) * K + k0 + skk,      Bs0 + chunk * 1024);
                gld_lds16(Bb + (size_t)(n0 + m) * K + k0 + 32 + skk, Bs1 + chunk * 1024);
            }
        } else {
            const int m = w * 16 + srow;
            gld_lds16(Bb + (size_t)(n0 + m) * K + k0 + skk,      Bs0 + w * 1024);
            gld_lds16(Bb + (size_t)(n0 + m) * K + k0 + 32 + skk, Bs1 + w * 1024);
        }
        __syncthreads();
        {   // subtile 0 (k0)
            bf16x8 af[4], bfr[NF];
            #pragma unroll
            for (int mi = 0; mi < 4; ++mi)
                af[mi] = *reinterpret_cast<const bf16x8*>(
                    As0 + (wr * 64 + mi * 16 + frow) * 64 + fk);
            #pragma unroll
            for (int ni = 0; ni < NF; ++ni)
                bfr[ni] = *reinterpret_cast<const bf16x8*>(
                    Bs0 + (wc * (NF * 16) + ni * 16 + frow) * 64 + fk);
            #pragma unroll
            for (int mi = 0; mi < 4; ++mi)
                #pragma unroll
                for (int ni = 0; ni < NF; ++ni)
                    acc[mi][ni] = __builtin_amdgcn_mfma_f32_16x16x32_bf16(
                        af[mi], bfr[ni], acc[mi][ni], 0, 0, 0);
        }
        {   // subtile 1 (k0+32)
            bf16x8 af[4], bfr[NF];
            #pragma unroll
            for (int mi = 0; mi < 4; ++mi)
                af[mi] = *reinterpret_cast<const bf16x8*>(
                    As1 + (wr * 64 + mi * 16 + frow) * 64 + fk);
            #pragma unroll
            for (int ni = 0; ni < NF; ++ni)
                bfr[ni] = *reinterpret_cast<const bf16x8*>(
                    Bs1 + (wc * (NF * 16) + ni * 16 + frow) * 64 + fk);
            #pragma unroll
            for (int mi = 0; mi < 4; ++mi)
                #pragma unroll
                for (int ni = 0; ni < NF; ++ni)
                    acc[mi][ni] = __builtin_amdgcn_mfma_f32_16x16x32_bf16(
                        af[mi], bfr[ni], acc[mi][ni], 0, 0, 0);
        }
        __syncthreads();
    }

    const int crow0 = (l >> 4) * 4;
    const int ccol  = l & 15;
    if (TRANS_OUT) {
        __hip_bfloat16* Yb = (__hip_bfloat16*)Y + (size_t)b * SP * O;
        #pragma unroll
        for (int ni = 0; ni < NF; ++ni) {
            const int col = n0 + wc * (NF * 16) + ni * 16 + ccol;
            if (col >= S_HW) continue;
            #pragma unroll
            for (int mi = 0; mi < 4; ++mi) {
                const int row0 = m0 + wr * 64 + mi * 16 + crow0;
                const float sc = (row0 < qrows) ? qscale : 1.f;
                float v0 = (acc[mi][ni][0] + bias[row0 + 0]) * sc;
                float v1 = (acc[mi][ni][1] + bias[row0 + 1]) * sc;
                float v2 = (acc[mi][ni][2] + bias[row0 + 2]) * sc;
                float v3 = (acc[mi][ni][3] + bias[row0 + 3]) * sc;
                uint2 pk;
                pk.x = f2h_bits(v0) | (f2h_bits(v1) << 16);
                pk.y = f2h_bits(v2) | (f2h_bits(v3) << 16);
                *reinterpret_cast<uint2*>(&Yb[(size_t)col * O + row0]) = pk;
            }
        }
    } else {
        float* Yb = (float*)Y + (size_t)b * O * S_HW;
        #pragma unroll
        for (int ni = 0; ni < NF; ++ni) {
            const int col = n0 + wc * (NF * 16) + ni * 16 + ccol;
            if (col >= S_HW) continue;
            #pragma unroll
            for (int mi = 0; mi < 4; ++mi) {
                #pragma unroll
                for (int r = 0; r < 4; ++r) {
                    const int row = m0 + wr * 64 + mi * 16 + crow0 + r;
                    float v = acc[mi][ni][r] + bias[row];
                    if (row < qrows) v *= qscale;
                    Yb[(size_t)row * S_HW + col] = v;
                }
            }
        }
    }
}

// ---------------------------------------------------------------------------
// Neighborhood attention, 2 threads/pixel, INTERLEAVED plane split:
// lane half h owns planes {2j+h} = channels {8j+4h..8j+4h+3}, j=0..3.
// Plane stride 994 dw (== +2 banks): half0 banks 2px, half1 banks 2px+2 ->
// 4 lanes/even-bank = b64 minimum, no extra conflicts (r12 fix #1).
// __launch_bounds__(512,4): 2 blocks/CU, 128-VGPR cap (r12 fix #2).
// ---------------------------------------------------------------------------
__global__ __launch_bounds__(512, 4) void na_attn_kernel(
    const __hip_bfloat16* __restrict__ qkvt, const float* __restrict__ rel_bias,
    __hip_bfloat16* __restrict__ outt)
{
    __shared__ alignas(16) char halo[8 * PLANE_B];   // 31.8 KB

    const int blk  = blockIdx.x;          // b*NH*16 + nh*16 + tile
    const int tile = blk & 15;
    const int bn   = blk >> 4;
    const int nh   = bn % NH_DIM;
    const int b    = bn / NH_DIM;
    const int th0  = (tile >> 2) * TB;
    const int tw0  = (tile & 3) * TB;

    const int tid  = threadIdx.x;
    const int px   = tid >> 1;            // 0..255 pixel within tile
    const int half = tid & 1;             // channel-interleave half
    const int ty = px >> 4, tx = px & 15;
    const int h = th0 + ty, w = tw0 + tx;
    const bool valid = (h < 56) && (w < 56);
    const int s = h * IMG_W + w;

    const __hip_bfloat16* base = qkvt + (size_t)b * SP * QKV_C;
    const int co = nh * 32;

    // ---- stage K halo: group g uint4 = ch 8g..8g+7; lo->plane 2g, hi->2g+1
    #pragma unroll
    for (int i = 0; i < 4; ++i) {
        const int idx = tid + i * 512;
        if (idx < NPX * 4) {
            const int p = idx >> 2, g = idx & 3;
            const int hy = p / HALO, hx = p - hy * HALO;
            const int y = min(max(th0 - 3 + hy, 0), 55);
            const int x = min(max(tw0 - 3 + hx, 0), 55);
            const uint4 v = *reinterpret_cast<const uint4*>(
                base + (size_t)(y * IMG_W + x) * QKV_C + C_DIM + co + g * 8);
            uint2 lo; lo.x = v.x; lo.y = v.y;
            uint2 hi; hi.x = v.z; hi.y = v.w;
            *reinterpret_cast<uint2*>(&halo[(2 * g + 0) * PLANE_B + p * 8]) = lo;
            *reinterpret_cast<uint2*>(&halo[(2 * g + 1) * PLANE_B + p * 8]) = hi;
        }
    }

    // ---- own q: this half's 16 channels = {8j+4h..+3}, j=0..3
    unsigned int qreg[8];
    if (valid) {
        #pragma unroll
        for (int j = 0; j < 4; ++j) {
            uint2 qv = *reinterpret_cast<const uint2*>(
                base + (size_t)s * QKV_C + co + 8 * j + 4 * half);
            qreg[2 * j]     = qv.x;
            qreg[2 * j + 1] = qv.y;
        }
    }
    __syncthreads();

    // ---- QK: 49 partial dots (16 ch) from planes 2j+half, pair-combined
    float logits[49];
    if (valid) {
        #pragma unroll
        for (int di = 0; di < 7; ++di) {
            #pragma unroll
            for (int dj = 0; dj < 7; ++dj) {
                const int hp = (ty + di) * HALO + (tx + dj);
                const char* hb = halo + hp * 8;
                float acc0 = 0.f, acc1 = 0.f;
                #pragma unroll
                for (int j = 0; j < 4; ++j) {
                    uint2 kk = *reinterpret_cast<const uint2*>(
                        hb + (2 * j + half) * PLANE_B);
#if __has_builtin(__builtin_amdgcn_fdot2)
                    acc0 = __builtin_amdgcn_fdot2(
                        __builtin_bit_cast(f16x2, qreg[2 * j]),
                        __builtin_bit_cast(f16x2, kk.x), acc0, false);
                    acc1 = __builtin_amdgcn_fdot2(
                        __builtin_bit_cast(f16x2, qreg[2 * j + 1]),
                        __builtin_bit_cast(f16x2, kk.y), acc1, false);
#else
                    f16x2 qa = __builtin_bit_cast(f16x2, qreg[2 * j]);
                    f16x2 qb = __builtin_bit_cast(f16x2, qreg[2 * j + 1]);
                    f16x2 ka = __builtin_bit_cast(f16x2, kk.x);
                    f16x2 kb = __builtin_bit_cast(f16x2, kk.y);
                    acc0 += (float)qa[0] * (float)ka[0] + (float)qa[1] * (float)ka[1];
                    acc1 += (float)qb[0] * (float)kb[0] + (float)qb[1] * (float)kb[1];
#endif
                }
                logits[di * 7 + dj] =
                    pair_sum(acc0 + acc1) + rel_bias[(nh * 7 + di) * 7 + dj];
            }
        }
    }
    __syncthreads();    // all K reads done before V overwrites

    // ---- stage V halo into the same buffer
    #pragma unroll
    for (int i = 0; i < 4; ++i) {
        const int idx = tid + i * 512;
        if (idx < NPX * 4) {
            const int p = idx >> 2, g = idx & 3;
            const int hy = p / HALO, hx = p - hy * HALO;
            const int y = min(max(th0 - 3 + hy, 0), 55);
            const int x = min(max(tw0 - 3 + hx, 0), 55);
            const uint4 v = *reinterpret_cast<const uint4*>(
                base + (size_t)(y * IMG_W + x) * QKV_C + 2 * C_DIM + co + g * 8);
            uint2 lo; lo.x = v.x; lo.y = v.y;
            uint2 hi; hi.x = v.z; hi.y = v.w;
            *reinterpret_cast<uint2*>(&halo[(2 * g + 0) * PLANE_B + p * 8]) = lo;
            *reinterpret_cast<uint2*>(&halo[(2 * g + 1) * PLANE_B + p * 8]) = hi;
        }
    }

    // ---- softmax (redundant per pair, deterministic); pack p to bf16 pairs
    unsigned int ppk[25];
    float inv = 0.f;
    if (valid) {
        float mx = logits[0];
        #pragma unroll
        for (int i = 1; i < 49; ++i) mx = fmaxf(mx, logits[i]);
        float sum = 0.f;
        #pragma unroll
        for (int i = 0; i < 24; ++i) {
            float e0 = __expf(logits[2 * i] - mx);
            float e1 = __expf(logits[2 * i + 1] - mx);
            sum += e0 + e1;
            ppk[i] = f2bf_bits(e0) << 16 | f2bf_bits(e1);
        }
        {
            float e0 = __expf(logits[48] - mx);
            sum += e0;
            ppk[24] = f2bf_bits(e0) << 16;
        }
        inv = 1.f / sum;
    }
    __syncthreads();

    // ---- PV: accumulate this half's 16 channels via fma_mix
    if (valid) {
        float o[16];
        #pragma unroll
        for (int c = 0; c < 16; ++c) o[c] = 0.f;

        #pragma unroll
        for (int n = 0; n < 49; ++n) {
            const unsigned int pu = ppk[n >> 1];
            const float pv = (n & 1) ? u2f(pu << 16) : u2f(pu & 0xFFFF0000u);
            const int di = n / 7, dj = n % 7;
            const int hp = (ty + di) * HALO + (tx + dj);
            const char* hb = halo + hp * 8;
            #pragma unroll
            for (int j = 0; j < 4; ++j) {
                uint2 vv = *reinterpret_cast<const uint2*>(
                    hb + (2 * j + half) * PLANE_B);
                f16x2 va = __builtin_bit_cast(f16x2, vv.x);
                f16x2 vb = __builtin_bit_cast(f16x2, vv.y);
                o[4 * j + 0] = fmaf((float)va[0], pv, o[4 * j + 0]);
                o[4 * j + 1] = fmaf((float)va[1], pv, o[4 * j + 1]);
                o[4 * j + 2] = fmaf((float)vb[0], pv, o[4 * j + 2]);
                o[4 * j + 3] = fmaf((float)vb[1], pv, o[4 * j + 3]);
            }
        }

        __hip_bfloat16* ob = outt + ((size_t)b * SP + s) * C_DIM + co + 4 * half;
        #pragma unroll
        for (int j = 0; j < 4; ++j) {
            uint2 pk;
            pk.x = f2bf_bits(o[4 * j + 0] * inv) | (f2bf_bits(o[4 * j + 1] * inv) << 16);
            pk.y = f2bf_bits(o[4 * j + 2] * inv) | (f2bf_bits(o[4 * j + 3] * inv) << 16);
            *reinterpret_cast<uint2*>(ob + 8 * j) = pk;
        }
    }
}

// ---------------------------------------------------------------------------
extern "C" void kernel_launch(void* const* d_in, const int* in_sizes, int n_in,
                              void* d_out, int out_size, void* d_ws, size_t ws_size,
                              hipStream_t stream) {
    const float* x        = (const float*)d_in[0];
    const float* w_qkv    = (const float*)d_in[1];
    const float* b_qkv    = (const float*)d_in[2];
    const float* w_proj   = (const float*)d_in[3];
    const float* b_proj   = (const float*)d_in[4];
    const float* rel_bias = (const float*)d_in[5];
    float* out = (float*)d_out;

    __hip_bfloat16* xt   = (__hip_bfloat16*)d_ws;
    __hip_bfloat16* wq   = xt + (size_t)4 * SP * C_DIM;
    __hip_bfloat16* wp   = wq + (size_t)QKV_C * C_DIM;
    __hip_bfloat16* qkvt = wp + (size_t)C_DIM * C_DIM;
    __hip_bfloat16* att  = qkvt + (size_t)4 * SP * QKV_C;

    const float scale = 0.17677669529663687f;  // 32^-0.5
    const int nwq = QKV_C * C_DIM, nwp = C_DIM * C_DIM;

    convert_w2_kernel<<<dim3((nwq + nwp + 255) / 256), 256, 0, stream>>>(
        w_qkv, nwq, wq, w_proj, nwp, wp);
    transpose_convert_kernel<<<dim3(98, 12, 4), dim3(256), 0, stream>>>(x, xt);

    // qkv projection: O=1152, K=384 -> [b][SP][1152] f16 (q pre-scaled)
    gemm_bf16_mfma<true, 4, __hip_bfloat16><<<dim3(25, 9, 4), 256, 0, stream>>>(
        wq, xt, b_qkv, qkvt, QKV_C, C_DIM, scale, C_DIM);

    // attention: 4 b * 12 heads * 16 tiles; 512 thr = 2 per pixel
    na_attn_kernel<<<dim3(4 * NH_DIM * 16), 512, 0, stream>>>(qkvt, rel_bias, att);

    // output projection: O=384, K=384, tile 128x64 -> 600 blocks, fp32 out
    gemm_bf16_mfma<false, 2, float><<<dim3(50, 3, 4), 256, 0, stream>>>(
        wp, att, b_proj, out, C_DIM, C_DIM, 1.f, 0);
}

// Round 14
// 93.925 us; speedup vs baseline: 1.1104x; 1.0793x over previous
//
#include <hip/hip_runtime.h>
#include <hip/hip_bf16.h>
#include <hip/hip_fp16.h>

// B=4, C=384, H=W=56 (S=3136, padded 3200), NH=12, HD=32, WS=7, pad=3.
#define S_HW 3136
#define SP   3200
#define IMG_W 56
#define C_DIM 384
#define NH_DIM 12
#define QKV_C 1152

// attention tiling
#define TB 16              // tile is TB x TB pixels
#define HALO 22            // TB + 6
#define NPX 484            // HALO*HALO
#define PLANE_B 3880       // NPX*8 rounded up (+8) to stagger plane banks

typedef float f32x4 __attribute__((ext_vector_type(4)));
typedef short bf16x8 __attribute__((ext_vector_type(8)));
typedef _Float16 f16x2 __attribute__((ext_vector_type(2)));

__device__ __forceinline__ void gld_lds16(const void* g, void* lds) {
    __builtin_amdgcn_global_load_lds(
        (const __attribute__((address_space(1))) void*)g,
        (__attribute__((address_space(3))) void*)lds, 16, 0, 0);
}

__device__ __forceinline__ float u2f(unsigned int u) { return __uint_as_float(u); }
__device__ __forceinline__ unsigned int f2bf_bits(float f) {
    unsigned int u = __float_as_uint(f);
    u += 0x7FFF + ((u >> 16) & 1);   // round-nearest-even
    return u >> 16;
}
__device__ __forceinline__ unsigned int f2h_bits(float f) {
    return (unsigned int)__half_as_ushort(__float2half(f));
}

// ---------------------------------------------------------------------------
__global__ __launch_bounds__(256) void convert_w2_kernel(
    const float* __restrict__ a, int na, __hip_bfloat16* __restrict__ oa,
    const float* __restrict__ b, int nb, __hip_bfloat16* __restrict__ ob)
{
    int i = blockIdx.x * 256 + threadIdx.x;
    if (i < na) oa[i] = __float2bfloat16(a[i]);
    else if (i < na + nb) ob[i - na] = __float2bfloat16(b[i - na]);
}

// ---------------------------------------------------------------------------
// x [4][384][3136] f32  ->  x_t [4][3200][384] bf16 (transpose + convert)
// ---------------------------------------------------------------------------
__global__ __launch_bounds__(256) void transpose_convert_kernel(
    const float* __restrict__ x, __hip_bfloat16* __restrict__ xt)
{
    __shared__ float t[32][33];
    const int b = blockIdx.z;
    const int c0 = blockIdx.y * 32, s0 = blockIdx.x * 32;
    const int tid = threadIdx.x;

    const int lc = tid >> 3, ls = (tid & 7) * 4;
    float4 v = *reinterpret_cast<const float4*>(
        &x[((size_t)b * C_DIM + c0 + lc) * S_HW + s0 + ls]);
    t[lc][ls + 0] = v.x; t[lc][ls + 1] = v.y;
    t[lc][ls + 2] = v.z; t[lc][ls + 3] = v.w;
    __syncthreads();

    const int ws = tid >> 3, wc = (tid & 7) * 4;
    uint2 pk;
    pk.x = f2bf_bits(t[wc + 0][ws]) | (f2bf_bits(t[wc + 1][ws]) << 16);
    pk.y = f2bf_bits(t[wc + 2][ws]) | (f2bf_bits(t[wc + 3][ws]) << 16);
    *reinterpret_cast<uint2*>(
        &xt[((size_t)b * SP + s0 + ws) * C_DIM + c0 + wc]) = pk;
}

// ---------------------------------------------------------------------------
// bf16 MFMA GEMM (m97 structure), tile 128 x (NF*32), 4 waves (2x2).
// 2 k-subtiles (BK=32 each) per barrier pair (r13: measured ~4 us win).
// Accumulation order identical to single-subtile version (bit-exact).
// ---------------------------------------------------------------------------
template <bool TRANS_OUT, int NF, typename OutT>
__global__ __launch_bounds__(256) void gemm_bf16_mfma(
    const __hip_bfloat16* __restrict__ A,    // [O][K]
    const __hip_bfloat16* __restrict__ Bt,   // [batch][SP][K]
    const float* __restrict__ bias,
    OutT* __restrict__ Y,
    int O, int K, float qscale, int qrows)
{
    constexpr int BN = NF * 32;
    __shared__ char smem[16384 + BN * 128];
    char* As0 = smem;                  // [128][32] bf16 linear, k0
    char* As1 = smem + 8192;           // k0+32
    char* Bs0 = smem + 16384;          // [BN][32], k0
    char* Bs1 = smem + 16384 + BN * 64;// k0+32

    const int b   = blockIdx.z;
    const int m0  = blockIdx.y * 128;
    const int n0  = blockIdx.x * BN;
    const int tid = threadIdx.x;
    const int w = tid >> 6, l = tid & 63;
    const int wr = w >> 1, wc = w & 1;

    const int srow = l >> 2;
    const int skk  = (l & 3) * 8;

    const __hip_bfloat16* Bb = Bt + (size_t)b * SP * K;

    f32x4 acc[4][NF];
    #pragma unroll
    for (int i = 0; i < 4; ++i)
        #pragma unroll
        for (int j = 0; j < NF; ++j) {
            f32x4 z = {0.f, 0.f, 0.f, 0.f};
            acc[i][j] = z;
        }

    const int frow = l & 15;
    const int fk   = (l >> 4) * 16;

    for (int k0 = 0; k0 < K; k0 += 64) {
        #pragma unroll
        for (int j = 0; j < 2; ++j) {
            const int chunk = w * 2 + j;
            const int m = chunk * 16 + srow;
            gld_lds16(A + (size_t)(m0 + m) * K + k0 + skk,      As0 + chunk * 1024);
            gld_lds16(A + (size_t)(m0 + m) * K + k0 + 32 + skk, As1 + chunk * 1024);
        }
        if (NF == 4) {
            #pragma unroll
            for (int j = 0; j < 2; ++j) {
                const int chunk = w * 2 + j;
                const int m = chunk * 16 + srow;
                gld_lds16(Bb + (size_t)(n0 + m) * K + k0 + skk,      Bs0 + chunk * 1024);
                gld_lds16(Bb + (size_t)(n0 + m) * K + k0 + 32 + skk, Bs1 + chunk * 1024);
            }
        } else {
            const int m = w * 16 + srow;
            gld_lds16(Bb + (size_t)(n0 + m) * K + k0 + skk,      Bs0 + w * 1024);
            gld_lds16(Bb + (size_t)(n0 + m) * K + k0 + 32 + skk, Bs1 + w * 1024);
        }
        __syncthreads();
        {   // subtile 0 (k0)
            bf16x8 af[4], bfr[NF];
            #pragma unroll
            for (int mi = 0; mi < 4; ++mi)
                af[mi] = *reinterpret_cast<const bf16x8*>(
                    As0 + (wr * 64 + mi * 16 + frow) * 64 + fk);
            #pragma unroll
            for (int ni = 0; ni < NF; ++ni)
                bfr[ni] = *reinterpret_cast<const bf16x8*>(
                    Bs0 + (wc * (NF * 16) + ni * 16 + frow) * 64 + fk);
            #pragma unroll
            for (int mi = 0; mi < 4; ++mi)
                #pragma unroll
                for (int ni = 0; ni < NF; ++ni)
                    acc[mi][ni] = __builtin_amdgcn_mfma_f32_16x16x32_bf16(
                        af[mi], bfr[ni], acc[mi][ni], 0, 0, 0);
        }
        {   // subtile 1 (k0+32)
            bf16x8 af[4], bfr[NF];
            #pragma unroll
            for (int mi = 0; mi < 4; ++mi)
                af[mi] = *reinterpret_cast<const bf16x8*>(
                    As1 + (wr * 64 + mi * 16 + frow) * 64 + fk);
            #pragma unroll
            for (int ni = 0; ni < NF; ++ni)
                bfr[ni] = *reinterpret_cast<const bf16x8*>(
                    Bs1 + (wc * (NF * 16) + ni * 16 + frow) * 64 + fk);
            #pragma unroll
            for (int mi = 0; mi < 4; ++mi)
                #pragma unroll
                for (int ni = 0; ni < NF; ++ni)
                    acc[mi][ni] = __builtin_amdgcn_mfma_f32_16x16x32_bf16(
                        af[mi], bfr[ni], acc[mi][ni], 0, 0, 0);
        }
        __syncthreads();
    }

    const int crow0 = (l >> 4) * 4;
    const int ccol  = l & 15;
    if (TRANS_OUT) {
        __hip_bfloat16* Yb = (__hip_bfloat16*)Y + (size_t)b * SP * O;
        #pragma unroll
        for (int ni = 0; ni < NF; ++ni) {
            const int col = n0 + wc * (NF * 16) + ni * 16 + ccol;
            if (col >= S_HW) continue;
            #pragma unroll
            for (int mi = 0; mi < 4; ++mi) {
                const int row0 = m0 + wr * 64 + mi * 16 + crow0;
                const float sc = (row0 < qrows) ? qscale : 1.f;
                float v0 = (acc[mi][ni][0] + bias[row0 + 0]) * sc;
                float v1 = (acc[mi][ni][1] + bias[row0 + 1]) * sc;
                float v2 = (acc[mi][ni][2] + bias[row0 + 2]) * sc;
                float v3 = (acc[mi][ni][3] + bias[row0 + 3]) * sc;
                uint2 pk;
                pk.x = f2h_bits(v0) | (f2h_bits(v1) << 16);
                pk.y = f2h_bits(v2) | (f2h_bits(v3) << 16);
                *reinterpret_cast<uint2*>(&Yb[(size_t)col * O + row0]) = pk;
            }
        }
    } else {
        float* Yb = (float*)Y + (size_t)b * O * S_HW;
        #pragma unroll
        for (int ni = 0; ni < NF; ++ni) {
            const int col = n0 + wc * (NF * 16) + ni * 16 + ccol;
            if (col >= S_HW) continue;
            #pragma unroll
            for (int mi = 0; mi < 4; ++mi) {
                #pragma unroll
                for (int r = 0; r < 4; ++r) {
                    const int row = m0 + wr * 64 + mi * 16 + crow0 + r;
                    float v = acc[mi][ni][r] + bias[row];
                    if (row < qrows) v *= qscale;
                    Yb[(size_t)row * S_HW + col] = v;
                }
            }
        }
    }
}

// ---------------------------------------------------------------------------
// Neighborhood attention (r11 kernel, best measured: 41.4 us). LDS-staged
// halo, 1 thread/pixel, q/k/v f16, QK fdot2, PV fma_mix.
// launch_bounds(256,2): 128-VGPR budget (compiler picks 112, zero spill).
// ---------------------------------------------------------------------------
__global__ __launch_bounds__(256, 2) void na_attn_kernel(
    const __hip_bfloat16* __restrict__ qkvt, const float* __restrict__ rel_bias,
    __hip_bfloat16* __restrict__ outt)
{
    __shared__ alignas(16) char halo[8 * PLANE_B];   // ~31 KB

    const int blk  = blockIdx.x;          // b*NH*16 + nh*16 + tile
    const int tile = blk & 15;
    const int bn   = blk >> 4;
    const int nh   = bn % NH_DIM;
    const int b    = bn / NH_DIM;
    const int th0  = (tile >> 2) * TB;
    const int tw0  = (tile & 3) * TB;

    const int tid = threadIdx.x;
    const int ty = tid >> 4, tx = tid & 15;
    const int h = th0 + ty, w = tw0 + tx;
    const bool valid = (h < 56) && (w < 56);
    const int s = h * IMG_W + w;

    const __hip_bfloat16* base = qkvt + (size_t)b * SP * QKV_C;
    const int co = nh * 32;

    // ---- stage K halo
    #pragma unroll
    for (int i = 0; i < 8; ++i) {
        const int idx = tid + i * 256;
        if (idx < NPX * 4) {
            const int px = idx >> 2, g = idx & 3;
            const int hy = px / HALO, hx = px - hy * HALO;
            const int y = min(max(th0 - 3 + hy, 0), 55);
            const int x = min(max(tw0 - 3 + hx, 0), 55);
            const uint4 v = *reinterpret_cast<const uint4*>(
                base + (size_t)(y * IMG_W + x) * QKV_C + C_DIM + co + g * 8);
            uint2 lo; lo.x = v.x; lo.y = v.y;
            uint2 hi; hi.x = v.z; hi.y = v.w;
            *reinterpret_cast<uint2*>(&halo[(2 * g + 0) * PLANE_B + px * 8]) = lo;
            *reinterpret_cast<uint2*>(&halo[(2 * g + 1) * PLANE_B + px * 8]) = hi;
        }
    }

    // ---- own q (f16 pairs kept packed)
    unsigned int qreg[16];
    if (valid) {
        const uint4* qp = reinterpret_cast<const uint4*>(base + (size_t)s * QKV_C + co);
        #pragma unroll
        for (int g = 0; g < 4; ++g) {
            uint4 qg = qp[g];
            qreg[4 * g + 0] = qg.x; qreg[4 * g + 1] = qg.y;
            qreg[4 * g + 2] = qg.z; qreg[4 * g + 3] = qg.w;
        }
    }
    __syncthreads();

    // ---- QK: 49 dots from LDS via v_dot2_f32_f16
    float logits[49];
    if (valid) {
        #pragma unroll
        for (int di = 0; di < 7; ++di) {
            #pragma unroll
            for (int dj = 0; dj < 7; ++dj) {
                const int hp = (ty + di) * HALO + (tx + dj);
                const char* hb = halo + hp * 8;
                float acc0 = 0.f, acc1 = 0.f;
                #pragma unroll
                for (int pl = 0; pl < 8; ++pl) {
                    uint2 kk = *reinterpret_cast<const uint2*>(hb + pl * PLANE_B);
#if __has_builtin(__builtin_amdgcn_fdot2)
                    acc0 = __builtin_amdgcn_fdot2(
                        __builtin_bit_cast(f16x2, qreg[2 * pl]),
                        __builtin_bit_cast(f16x2, kk.x), acc0, false);
                    acc1 = __builtin_amdgcn_fdot2(
                        __builtin_bit_cast(f16x2, qreg[2 * pl + 1]),
                        __builtin_bit_cast(f16x2, kk.y), acc1, false);
#else
                    f16x2 qa = __builtin_bit_cast(f16x2, qreg[2 * pl]);
                    f16x2 qb = __builtin_bit_cast(f16x2, qreg[2 * pl + 1]);
                    f16x2 ka = __builtin_bit_cast(f16x2, kk.x);
                    f16x2 kb = __builtin_bit_cast(f16x2, kk.y);
                    acc0 += (float)qa[0] * (float)ka[0] + (float)qa[1] * (float)ka[1];
                    acc1 += (float)qb[0] * (float)kb[0] + (float)qb[1] * (float)kb[1];
#endif
                }
                logits[di * 7 + dj] = acc0 + acc1 + rel_bias[(nh * 7 + di) * 7 + dj];
            }
        }
    }
    __syncthreads();    // all K reads done before V overwrites

    // ---- stage V halo (f16) into the same buffer
    #pragma unroll
    for (int i = 0; i < 8; ++i) {
        const int idx = tid + i * 256;
        if (idx < NPX * 4) {
            const int px = idx >> 2, g = idx & 3;
            const int hy = px / HALO, hx = px - hy * HALO;
            const int y = min(max(th0 - 3 + hy, 0), 55);
            const int x = min(max(tw0 - 3 + hx, 0), 55);
            const uint4 v = *reinterpret_cast<const uint4*>(
                base + (size_t)(y * IMG_W + x) * QKV_C + 2 * C_DIM + co + g * 8);
            uint2 lo; lo.x = v.x; lo.y = v.y;
            uint2 hi; hi.x = v.z; hi.y = v.w;
            *reinterpret_cast<uint2*>(&halo[(2 * g + 0) * PLANE_B + px * 8]) = lo;
            *reinterpret_cast<uint2*>(&halo[(2 * g + 1) * PLANE_B + px * 8]) = hi;
        }
    }

    // ---- softmax (overlaps V staging latency); pack p to bf16 pairs
    unsigned int ppk[25];
    float inv = 0.f;
    if (valid) {
        float mx = logits[0];
        #pragma unroll
        for (int i = 1; i < 49; ++i) mx = fmaxf(mx, logits[i]);
        float sum = 0.f;
        #pragma unroll
        for (int i = 0; i < 24; ++i) {
            float e0 = __expf(logits[2 * i] - mx);
            float e1 = __expf(logits[2 * i + 1] - mx);
            sum += e0 + e1;
            ppk[i] = f2bf_bits(e0) << 16 | f2bf_bits(e1);
        }
        {
            float e0 = __expf(logits[48] - mx);
            sum += e0;
            ppk[24] = f2bf_bits(e0) << 16;
        }
        inv = 1.f / sum;
    }
    __syncthreads();

    // ---- PV: accumulate o from LDS via fma_mix (f16 v, f32 accum)
    if (valid) {
        float o[32];
        #pragma unroll
        for (int c = 0; c < 32; ++c) o[c] = 0.f;

        #pragma unroll
        for (int n = 0; n < 49; ++n) {
            const unsigned int pu = ppk[n >> 1];
            const float pv = (n & 1) ? u2f(pu << 16) : u2f(pu & 0xFFFF0000u);
            const int di = n / 7, dj = n % 7;
            const int hp = (ty + di) * HALO + (tx + dj);
            const char* hb = halo + hp * 8;
            #pragma unroll
            for (int pl = 0; pl < 8; ++pl) {
                uint2 vv = *reinterpret_cast<const uint2*>(hb + pl * PLANE_B);
                f16x2 va = __builtin_bit_cast(f16x2, vv.x);
                f16x2 vb = __builtin_bit_cast(f16x2, vv.y);
                o[4 * pl + 0] = fmaf((float)va[0], pv, o[4 * pl + 0]);
                o[4 * pl + 1] = fmaf((float)va[1], pv, o[4 * pl + 1]);
                o[4 * pl + 2] = fmaf((float)vb[0], pv, o[4 * pl + 2]);
                o[4 * pl + 3] = fmaf((float)vb[1], pv, o[4 * pl + 3]);
            }
        }

        uint4* dst = reinterpret_cast<uint4*>(outt + ((size_t)b * SP + s) * C_DIM + co);
        #pragma unroll
        for (int g = 0; g < 4; ++g) {
            uint4 pk;
            pk.x = f2bf_bits(o[8 * g + 0] * inv) | (f2bf_bits(o[8 * g + 1] * inv) << 16);
            pk.y = f2bf_bits(o[8 * g + 2] * inv) | (f2bf_bits(o[8 * g + 3] * inv) << 16);
            pk.z = f2bf_bits(o[8 * g + 4] * inv) | (f2bf_bits(o[8 * g + 5] * inv) << 16);
            pk.w = f2bf_bits(o[8 * g + 6] * inv) | (f2bf_bits(o[8 * g + 7] * inv) << 16);
            dst[g] = pk;
        }
    }
}

// ---------------------------------------------------------------------------
extern "C" void kernel_launch(void* const* d_in, const int* in_sizes, int n_in,
                              void* d_out, int out_size, void* d_ws, size_t ws_size,
                              hipStream_t stream) {
    const float* x        = (const float*)d_in[0];
    const float* w_qkv    = (const float*)d_in[1];
    const float* b_qkv    = (const float*)d_in[2];
    const float* w_proj   = (const float*)d_in[3];
    const float* b_proj   = (const float*)d_in[4];
    const float* rel_bias = (const float*)d_in[5];
    float* out = (float*)d_out;

    __hip_bfloat16* xt   = (__hip_bfloat16*)d_ws;
    __hip_bfloat16* wq   = xt + (size_t)4 * SP * C_DIM;
    __hip_bfloat16* wp   = wq + (size_t)QKV_C * C_DIM;
    __hip_bfloat16* qkvt = wp + (size_t)C_DIM * C_DIM;
    __hip_bfloat16* att  = qkvt + (size_t)4 * SP * QKV_C;

    const float scale = 0.17677669529663687f;  // 32^-0.5
    const int nwq = QKV_C * C_DIM, nwp = C_DIM * C_DIM;

    convert_w2_kernel<<<dim3((nwq + nwp + 255) / 256), 256, 0, stream>>>(
        w_qkv, nwq, wq, w_proj, nwp, wp);
    transpose_convert_kernel<<<dim3(98, 12, 4), dim3(256), 0, stream>>>(x, xt);

    // qkv projection: O=1152, K=384 -> [b][SP][1152] f16 (q pre-scaled)
    gemm_bf16_mfma<true, 4, __hip_bfloat16><<<dim3(25, 9, 4), 256, 0, stream>>>(
        wq, xt, b_qkv, qkvt, QKV_C, C_DIM, scale, C_DIM);

    // attention: 4 b * 12 heads * 16 tiles (4x4 of 16x16 px)
    na_attn_kernel<<<dim3(4 * NH_DIM * 16), 256, 0, stream>>>(qkvt, rel_bias, att);

    // output projection: O=384, K=384, tile 128x64 -> 600 blocks, fp32 out
    gemm_bf16_mfma<false, 2, float><<<dim3(50, 3, 4), 256, 0, stream>>>(
        wp, att, b_proj, out, C_DIM, C_DIM, 1.f, 0);
}

// Round 15
// 89.215 us; speedup vs baseline: 1.1691x; 1.0528x over previous
//
#include <hip/hip_runtime.h>
#include <hip/hip_bf16.h>
#include <hip/hip_fp16.h>

// B=4, C=384, H=W=56 (S=3136, padded 3200), NH=12, HD=32, WS=7, pad=3.
#define S_HW 3136
#define SP   3200
#define IMG_W 56
#define C_DIM 384
#define NH_DIM 12
#define QKV_C 1152

// attention tiling
#define TB 16              // tile is TB x TB pixels
#define HALO 22            // TB + 6
#define NPX 484            // HALO*HALO
#define PLANE_B 3880       // NPX*8 rounded up (+8) to stagger plane banks

typedef float f32x4 __attribute__((ext_vector_type(4)));
typedef short bf16x8 __attribute__((ext_vector_type(8)));
typedef _Float16 f16x2 __attribute__((ext_vector_type(2)));

__device__ __forceinline__ void gld_lds16(const void* g, void* lds) {
    __builtin_amdgcn_global_load_lds(
        (const __attribute__((address_space(1))) void*)g,
        (__attribute__((address_space(3))) void*)lds, 16, 0, 0);
}

__device__ __forceinline__ float u2f(unsigned int u) { return __uint_as_float(u); }
__device__ __forceinline__ unsigned int f2bf_bits(float f) {
    unsigned int u = __float_as_uint(f);
    u += 0x7FFF + ((u >> 16) & 1);   // round-nearest-even
    return u >> 16;
}
__device__ __forceinline__ unsigned int f2h_bits(float f) {
    return (unsigned int)__half_as_ushort(__float2half(f));
}

// ---------------------------------------------------------------------------
// Fused prep: z<4 -> x [4][384][3136] f32 -> x_t [4][3200][384] bf16
//             z==4 -> both weight tensors f32 -> bf16 (one launch saved)
// ---------------------------------------------------------------------------
__global__ __launch_bounds__(256) void prep_kernel(
    const float* __restrict__ x, __hip_bfloat16* __restrict__ xt,
    const float* __restrict__ wa, int na, __hip_bfloat16* __restrict__ oa,
    const float* __restrict__ wb, int nb, __hip_bfloat16* __restrict__ ob)
{
    const int tid = threadIdx.x;
    if (blockIdx.z == 4) {
        const int bid  = blockIdx.y * 98 + blockIdx.x;    // 0..1175
        const int base = bid * 512 + tid;
        #pragma unroll
        for (int r = 0; r < 2; ++r) {
            const int i = base + r * 256;
            if (i < na) oa[i] = __float2bfloat16(wa[i]);
            else if (i < na + nb) ob[i - na] = __float2bfloat16(wb[i - na]);
        }
        return;
    }
    __shared__ float t[32][33];
    const int b = blockIdx.z;
    const int c0 = blockIdx.y * 32, s0 = blockIdx.x * 32;

    const int lc = tid >> 3, ls = (tid & 7) * 4;
    float4 v = *reinterpret_cast<const float4*>(
        &x[((size_t)b * C_DIM + c0 + lc) * S_HW + s0 + ls]);
    t[lc][ls + 0] = v.x; t[lc][ls + 1] = v.y;
    t[lc][ls + 2] = v.z; t[lc][ls + 3] = v.w;
    __syncthreads();

    const int ws = tid >> 3, wc = (tid & 7) * 4;
    uint2 pk;
    pk.x = f2bf_bits(t[wc + 0][ws]) | (f2bf_bits(t[wc + 1][ws]) << 16);
    pk.y = f2bf_bits(t[wc + 2][ws]) | (f2bf_bits(t[wc + 3][ws]) << 16);
    *reinterpret_cast<uint2*>(
        &xt[((size_t)b * SP + s0 + ws) * C_DIM + c0 + wc]) = pk;
}

// ---------------------------------------------------------------------------
// bf16 MFMA GEMM (m97 structure), tile 128 x (NF*32), 4 waves (2x2).
// 2 k-subtiles (BK=32 each) per barrier pair (r13: measured ~4 us win).
// ---------------------------------------------------------------------------
template <bool TRANS_OUT, int NF, typename OutT>
__global__ __launch_bounds__(256) void gemm_bf16_mfma(
    const __hip_bfloat16* __restrict__ A,    // [O][K]
    const __hip_bfloat16* __restrict__ Bt,   // [batch][SP][K]
    const float* __restrict__ bias,
    OutT* __restrict__ Y,
    int O, int K, float qscale, int qrows)
{
    constexpr int BN = NF * 32;
    __shared__ char smem[16384 + BN * 128];
    char* As0 = smem;                  // [128][32] bf16 linear, k0
    char* As1 = smem + 8192;           // k0+32
    char* Bs0 = smem + 16384;          // [BN][32], k0
    char* Bs1 = smem + 16384 + BN * 64;// k0+32

    const int b   = blockIdx.z;
    const int m0  = blockIdx.y * 128;
    const int n0  = blockIdx.x * BN;
    const int tid = threadIdx.x;
    const int w = tid >> 6, l = tid & 63;
    const int wr = w >> 1, wc = w & 1;

    const int srow = l >> 2;
    const int skk  = (l & 3) * 8;

    const __hip_bfloat16* Bb = Bt + (size_t)b * SP * K;

    f32x4 acc[4][NF];
    #pragma unroll
    for (int i = 0; i < 4; ++i)
        #pragma unroll
        for (int j = 0; j < NF; ++j) {
            f32x4 z = {0.f, 0.f, 0.f, 0.f};
            acc[i][j] = z;
        }

    const int frow = l & 15;
    const int fk   = (l >> 4) * 16;

    for (int k0 = 0; k0 < K; k0 += 64) {
        #pragma unroll
        for (int j = 0; j < 2; ++j) {
            const int chunk = w * 2 + j;
            const int m = chunk * 16 + srow;
            gld_lds16(A + (size_t)(m0 + m) * K + k0 + skk,      As0 + chunk * 1024);
            gld_lds16(A + (size_t)(m0 + m) * K + k0 + 32 + skk, As1 + chunk * 1024);
        }
        if (NF == 4) {
            #pragma unroll
            for (int j = 0; j < 2; ++j) {
                const int chunk = w * 2 + j;
                const int m = chunk * 16 + srow;
                gld_lds16(Bb + (size_t)(n0 + m) * K + k0 + skk,      Bs0 + chunk * 1024);
                gld_lds16(Bb + (size_t)(n0 + m) * K + k0 + 32 + skk, Bs1 + chunk * 1024);
            }
        } else {
            const int m = w * 16 + srow;
            gld_lds16(Bb + (size_t)(n0 + m) * K + k0 + skk,      Bs0 + w * 1024);
            gld_lds16(Bb + (size_t)(n0 + m) * K + k0 + 32 + skk, Bs1 + w * 1024);
        }
        __syncthreads();
        {   // subtile 0 (k0)
            bf16x8 af[4], bfr[NF];
            #pragma unroll
            for (int mi = 0; mi < 4; ++mi)
                af[mi] = *reinterpret_cast<const bf16x8*>(
                    As0 + (wr * 64 + mi * 16 + frow) * 64 + fk);
            #pragma unroll
            for (int ni = 0; ni < NF; ++ni)
                bfr[ni] = *reinterpret_cast<const bf16x8*>(
                    Bs0 + (wc * (NF * 16) + ni * 16 + frow) * 64 + fk);
            #pragma unroll
            for (int mi = 0; mi < 4; ++mi)
                #pragma unroll
                for (int ni = 0; ni < NF; ++ni)
                    acc[mi][ni] = __builtin_amdgcn_mfma_f32_16x16x32_bf16(
                        af[mi], bfr[ni], acc[mi][ni], 0, 0, 0);
        }
        {   // subtile 1 (k0+32)
            bf16x8 af[4], bfr[NF];
            #pragma unroll
            for (int mi = 0; mi < 4; ++mi)
                af[mi] = *reinterpret_cast<const bf16x8*>(
                    As1 + (wr * 64 + mi * 16 + frow) * 64 + fk);
            #pragma unroll
            for (int ni = 0; ni < NF; ++ni)
                bfr[ni] = *reinterpret_cast<const bf16x8*>(
                    Bs1 + (wc * (NF * 16) + ni * 16 + frow) * 64 + fk);
            #pragma unroll
            for (int mi = 0; mi < 4; ++mi)
                #pragma unroll
                for (int ni = 0; ni < NF; ++ni)
                    acc[mi][ni] = __builtin_amdgcn_mfma_f32_16x16x32_bf16(
                        af[mi], bfr[ni], acc[mi][ni], 0, 0, 0);
        }
        __syncthreads();
    }

    const int crow0 = (l >> 4) * 4;
    const int ccol  = l & 15;
    if (TRANS_OUT) {
        __hip_bfloat16* Yb = (__hip_bfloat16*)Y + (size_t)b * SP * O;
        #pragma unroll
        for (int ni = 0; ni < NF; ++ni) {
            const int col = n0 + wc * (NF * 16) + ni * 16 + ccol;
            if (col >= S_HW) continue;
            #pragma unroll
            for (int mi = 0; mi < 4; ++mi) {
                const int row0 = m0 + wr * 64 + mi * 16 + crow0;
                const float sc = (row0 < qrows) ? qscale : 1.f;
                float v0 = (acc[mi][ni][0] + bias[row0 + 0]) * sc;
                float v1 = (acc[mi][ni][1] + bias[row0 + 1]) * sc;
                float v2 = (acc[mi][ni][2] + bias[row0 + 2]) * sc;
                float v3 = (acc[mi][ni][3] + bias[row0 + 3]) * sc;
                uint2 pk;
                pk.x = f2h_bits(v0) | (f2h_bits(v1) << 16);
                pk.y = f2h_bits(v2) | (f2h_bits(v3) << 16);
                *reinterpret_cast<uint2*>(&Yb[(size_t)col * O + row0]) = pk;
            }
        }
    } else {
        float* Yb = (float*)Y + (size_t)b * O * S_HW;
        #pragma unroll
        for (int ni = 0; ni < NF; ++ni) {
            const int col = n0 + wc * (NF * 16) + ni * 16 + ccol;
            if (col >= S_HW) continue;
            #pragma unroll
            for (int mi = 0; mi < 4; ++mi) {
                #pragma unroll
                for (int r = 0; r < 4; ++r) {
                    const int row = m0 + wr * 64 + mi * 16 + crow0 + r;
                    float v = acc[mi][ni][r] + bias[row];
                    if (row < qrows) v *= qscale;
                    Yb[(size_t)row * S_HW + col] = v;
                }
            }
        }
    }
}

// ---------------------------------------------------------------------------
// Neighborhood attention (r11 structure + half-V register prefetch).
// LDS-staged halo, 1 thread/pixel, q/k/v f16, QK fdot2, PV fma_mix.
// V-chunks 0..3 (idx<1024<1936: guard-free) loaded to regs BEFORE QK so their
// L2 latency hides under QK compute; chunks 4..7 staged post-QK as before.
// launch_bounds(256,2): 128-VGPR cap (r11: compiler chose 112, zero spill).
// ---------------------------------------------------------------------------
__global__ __launch_bounds__(256, 2) void na_attn_kernel(
    const __hip_bfloat16* __restrict__ qkvt, const float* __restrict__ rel_bias,
    __hip_bfloat16* __restrict__ outt)
{
    __shared__ alignas(16) char halo[8 * PLANE_B];   // ~31 KB

    const int blk  = blockIdx.x;          // b*NH*16 + nh*16 + tile
    const int tile = blk & 15;
    const int bn   = blk >> 4;
    const int nh   = bn % NH_DIM;
    const int b    = bn / NH_DIM;
    const int th0  = (tile >> 2) * TB;
    const int tw0  = (tile & 3) * TB;

    const int tid = threadIdx.x;
    const int ty = tid >> 4, tx = tid & 15;
    const int h = th0 + ty, w = tw0 + tx;
    const bool valid = (h < 56) && (w < 56);
    const int s = h * IMG_W + w;

    const __hip_bfloat16* base = qkvt + (size_t)b * SP * QKV_C;
    const int co = nh * 32;

    // ---- stage K halo
    #pragma unroll
    for (int i = 0; i < 8; ++i) {
        const int idx = tid + i * 256;
        if (idx < NPX * 4) {
            const int px = idx >> 2, g = idx & 3;
            const int hy = px / HALO, hx = px - hy * HALO;
            const int y = min(max(th0 - 3 + hy, 0), 55);
            const int x = min(max(tw0 - 3 + hx, 0), 55);
            const uint4 v = *reinterpret_cast<const uint4*>(
                base + (size_t)(y * IMG_W + x) * QKV_C + C_DIM + co + g * 8);
            uint2 lo; lo.x = v.x; lo.y = v.y;
            uint2 hi; hi.x = v.z; hi.y = v.w;
            *reinterpret_cast<uint2*>(&halo[(2 * g + 0) * PLANE_B + px * 8]) = lo;
            *reinterpret_cast<uint2*>(&halo[(2 * g + 1) * PLANE_B + px * 8]) = hi;
        }
    }

    // ---- prefetch first half of V into registers (hidden under QK)
    uint4 vstage[4];
    #pragma unroll
    for (int i = 0; i < 4; ++i) {
        const int idx = tid + i * 256;       // < 1024 < NPX*4: no guard
        const int px = idx >> 2, g = idx & 3;
        const int hy = px / HALO, hx = px - hy * HALO;
        const int y = min(max(th0 - 3 + hy, 0), 55);
        const int x = min(max(tw0 - 3 + hx, 0), 55);
        vstage[i] = *reinterpret_cast<const uint4*>(
            base + (size_t)(y * IMG_W + x) * QKV_C + 2 * C_DIM + co + g * 8);
    }

    // ---- own q (f16 pairs kept packed)
    unsigned int qreg[16];
    if (valid) {
        const uint4* qp = reinterpret_cast<const uint4*>(base + (size_t)s * QKV_C + co);
        #pragma unroll
        for (int g = 0; g < 4; ++g) {
            uint4 qg = qp[g];
            qreg[4 * g + 0] = qg.x; qreg[4 * g + 1] = qg.y;
            qreg[4 * g + 2] = qg.z; qreg[4 * g + 3] = qg.w;
        }
    }
    __syncthreads();

    // ---- QK: 49 dots from LDS via v_dot2_f32_f16
    float logits[49];
    if (valid) {
        #pragma unroll
        for (int di = 0; di < 7; ++di) {
            #pragma unroll
            for (int dj = 0; dj < 7; ++dj) {
                const int hp = (ty + di) * HALO + (tx + dj);
                const char* hb = halo + hp * 8;
                float acc0 = 0.f, acc1 = 0.f;
                #pragma unroll
                for (int pl = 0; pl < 8; ++pl) {
                    uint2 kk = *reinterpret_cast<const uint2*>(hb + pl * PLANE_B);
#if __has_builtin(__builtin_amdgcn_fdot2)
                    acc0 = __builtin_amdgcn_fdot2(
                        __builtin_bit_cast(f16x2, qreg[2 * pl]),
                        __builtin_bit_cast(f16x2, kk.x), acc0, false);
                    acc1 = __builtin_amdgcn_fdot2(
                        __builtin_bit_cast(f16x2, qreg[2 * pl + 1]),
                        __builtin_bit_cast(f16x2, kk.y), acc1, false);
#else
                    f16x2 qa = __builtin_bit_cast(f16x2, qreg[2 * pl]);
                    f16x2 qb = __builtin_bit_cast(f16x2, qreg[2 * pl + 1]);
                    f16x2 ka = __builtin_bit_cast(f16x2, kk.x);
                    f16x2 kb = __builtin_bit_cast(f16x2, kk.y);
                    acc0 += (float)qa[0] * (float)ka[0] + (float)qa[1] * (float)ka[1];
                    acc1 += (float)qb[0] * (float)kb[0] + (float)qb[1] * (float)kb[1];
#endif
                }
                logits[di * 7 + dj] = acc0 + acc1 + rel_bias[(nh * 7 + di) * 7 + dj];
            }
        }
    }
    __syncthreads();    // all K reads done before V overwrites

    // ---- write prefetched V chunks; stage remaining half from global
    #pragma unroll
    for (int i = 0; i < 4; ++i) {
        const int idx = tid + i * 256;
        const int px = idx >> 2, g = idx & 3;
        uint2 lo; lo.x = vstage[i].x; lo.y = vstage[i].y;
        uint2 hi; hi.x = vstage[i].z; hi.y = vstage[i].w;
        *reinterpret_cast<uint2*>(&halo[(2 * g + 0) * PLANE_B + px * 8]) = lo;
        *reinterpret_cast<uint2*>(&halo[(2 * g + 1) * PLANE_B + px * 8]) = hi;
    }
    #pragma unroll
    for (int i = 4; i < 8; ++i) {
        const int idx = tid + i * 256;
        if (idx < NPX * 4) {
            const int px = idx >> 2, g = idx & 3;
            const int hy = px / HALO, hx = px - hy * HALO;
            const int y = min(max(th0 - 3 + hy, 0), 55);
            const int x = min(max(tw0 - 3 + hx, 0), 55);
            const uint4 v = *reinterpret_cast<const uint4*>(
                base + (size_t)(y * IMG_W + x) * QKV_C + 2 * C_DIM + co + g * 8);
            uint2 lo; lo.x = v.x; lo.y = v.y;
            uint2 hi; hi.x = v.z; hi.y = v.w;
            *reinterpret_cast<uint2*>(&halo[(2 * g + 0) * PLANE_B + px * 8]) = lo;
            *reinterpret_cast<uint2*>(&halo[(2 * g + 1) * PLANE_B + px * 8]) = hi;
        }
    }

    // ---- softmax (overlaps V staging latency); pack p to bf16 pairs
    unsigned int ppk[25];
    float inv = 0.f;
    if (valid) {
        float mx = logits[0];
        #pragma unroll
        for (int i = 1; i < 49; ++i) mx = fmaxf(mx, logits[i]);
        float sum = 0.f;
        #pragma unroll
        for (int i = 0; i < 24; ++i) {
            float e0 = __expf(logits[2 * i] - mx);
            float e1 = __expf(logits[2 * i + 1] - mx);
            sum += e0 + e1;
            ppk[i] = f2bf_bits(e0) << 16 | f2bf_bits(e1);
        }
        {
            float e0 = __expf(logits[48] - mx);
            sum += e0;
            ppk[24] = f2bf_bits(e0) << 16;
        }
        inv = 1.f / sum;
    }
    __syncthreads();

    // ---- PV: accumulate o from LDS via fma_mix (f16 v, f32 accum)
    if (valid) {
        float o[32];
        #pragma unroll
        for (int c = 0; c < 32; ++c) o[c] = 0.f;

        #pragma unroll
        for (int n = 0; n < 49; ++n) {
            const unsigned int pu = ppk[n >> 1];
            const float pv = (n & 1) ? u2f(pu << 16) : u2f(pu & 0xFFFF0000u);
            const int di = n / 7, dj = n % 7;
            const int hp = (ty + di) * HALO + (tx + dj);
            const char* hb = halo + hp * 8;
            #pragma unroll
            for (int pl = 0; pl < 8; ++pl) {
                uint2 vv = *reinterpret_cast<const uint2*>(hb + pl * PLANE_B);
                f16x2 va = __builtin_bit_cast(f16x2, vv.x);
                f16x2 vb = __builtin_bit_cast(f16x2, vv.y);
                o[4 * pl + 0] = fmaf((float)va[0], pv, o[4 * pl + 0]);
                o[4 * pl + 1] = fmaf((float)va[1], pv, o[4 * pl + 1]);
                o[4 * pl + 2] = fmaf((float)vb[0], pv, o[4 * pl + 2]);
                o[4 * pl + 3] = fmaf((float)vb[1], pv, o[4 * pl + 3]);
            }
        }

        uint4* dst = reinterpret_cast<uint4*>(outt + ((size_t)b * SP + s) * C_DIM + co);
        #pragma unroll
        for (int g = 0; g < 4; ++g) {
            uint4 pk;
            pk.x = f2bf_bits(o[8 * g + 0] * inv) | (f2bf_bits(o[8 * g + 1] * inv) << 16);
            pk.y = f2bf_bits(o[8 * g + 2] * inv) | (f2bf_bits(o[8 * g + 3] * inv) << 16);
            pk.z = f2bf_bits(o[8 * g + 4] * inv) | (f2bf_bits(o[8 * g + 5] * inv) << 16);
            pk.w = f2bf_bits(o[8 * g + 6] * inv) | (f2bf_bits(o[8 * g + 7] * inv) << 16);
            dst[g] = pk;
        }
    }
}

// ---------------------------------------------------------------------------
extern "C" void kernel_launch(void* const* d_in, const int* in_sizes, int n_in,
                              void* d_out, int out_size, void* d_ws, size_t ws_size,
                              hipStream_t stream) {
    const float* x        = (const float*)d_in[0];
    const float* w_qkv    = (const float*)d_in[1];
    const float* b_qkv    = (const float*)d_in[2];
    const float* w_proj   = (const float*)d_in[3];
    const float* b_proj   = (const float*)d_in[4];
    const float* rel_bias = (const float*)d_in[5];
    float* out = (float*)d_out;

    __hip_bfloat16* xt   = (__hip_bfloat16*)d_ws;
    __hip_bfloat16* wq   = xt + (size_t)4 * SP * C_DIM;
    __hip_bfloat16* wp   = wq + (size_t)QKV_C * C_DIM;
    __hip_bfloat16* qkvt = wp + (size_t)C_DIM * C_DIM;
    __hip_bfloat16* att  = qkvt + (size_t)4 * SP * QKV_C;

    const float scale = 0.17677669529663687f;  // 32^-0.5
    const int nwq = QKV_C * C_DIM, nwp = C_DIM * C_DIM;

    // fused transpose + weight conversion (z==4 handles weights)
    prep_kernel<<<dim3(98, 12, 5), 256, 0, stream>>>(
        x, xt, w_qkv, nwq, wq, w_proj, nwp, wp);

    // qkv projection: O=1152, K=384 -> [b][SP][1152] f16 (q pre-scaled)
    gemm_bf16_mfma<true, 4, __hip_bfloat16><<<dim3(25, 9, 4), 256, 0, stream>>>(
        wq, xt, b_qkv, qkvt, QKV_C, C_DIM, scale, C_DIM);

    // attention: 4 b * 12 heads * 16 tiles (4x4 of 16x16 px)
    na_attn_kernel<<<dim3(4 * NH_DIM * 16), 256, 0, stream>>>(qkvt, rel_bias, att);

    // output projection: O=384, K=384, tile 128x64 -> 600 blocks, fp32 out
    gemm_bf16_mfma<false, 2, float><<<dim3(50, 3, 4), 256, 0, stream>>>(
        wp, att, b_proj, out, C_DIM, C_DIM, 1.f, 0);
}